// Round 3
// baseline (2164.871 us; speedup 1.0000x reference)
//
#include <hip/hip_runtime.h>
#include <cstdint>

typedef __attribute__((ext_vector_type(4))) _Float16 f16x4;
typedef __attribute__((ext_vector_type(8))) _Float16 f16x8;
typedef __attribute__((ext_vector_type(4))) float f32x4;

#define D_DIM 1024
#define H_DIM 4096
#define N_BATCH 16
#define BS_ROWS 8192
#define K_SEL 524288u
#define SH_PER_B 2097152   // S*H per batch
#define LDSW 40            // halves per LDS row (80B; 16B-aligned rows; <=2-way bank alias)

// order-isomorphic fp32 -> uint32 key (larger float <=> larger key)
__device__ __forceinline__ unsigned fenc(float v){
  unsigned u = __float_as_uint(v);
  return (u & 0x80000000u) ? ~u : (u | 0x80000000u);
}

enum { MODE_G1 = 0, MODE_G2 = 1, MODE_UPMOD = 2, MODE_DOWN = 3 };

// C = A[M,K] * Bsel[N,K]^T + bias.
// SPLIT: 2-way fp16-split on A and B (3 MFMAs: hi*hi + hi*lo + lo*hi) ~ fp32 accuracy.
// AF16:  A in global is fp16 (Araw=hi, Alo2=lo if SPLIT); else fp32 (split at staging).
// MODE_G1:    Chi/Clo(fp16 pair) = split(relu(.))
// MODE_G2:    keys[lrow*N+gc] = fenc(.); Mkey[b,gc] max= key   (no C)
// MODE_UPMOD: B/bias row-selected by mask; C16 = silu(.)
// MODE_DOWN:  C32 = .
template<int MODE, bool SPLIT, bool AF16>
__global__ __launch_bounds__(256)
void gemm_bt(const void* __restrict__ Araw, const _Float16* __restrict__ Alo2,
             const float* __restrict__ B0, const float* __restrict__ B1,
             const float* __restrict__ bias0, const float* __restrict__ bias1,
             const unsigned* __restrict__ mask,
             void* __restrict__ Craw, _Float16* __restrict__ Clo,
             unsigned* __restrict__ keys, unsigned* __restrict__ Mkey,
             int M, int N, int K, int m_base)
{
  __shared__ _Float16 Ah[128][LDSW];
  __shared__ _Float16 Bh[128][LDSW];
  __shared__ _Float16 Al[SPLIT ? 128 : 1][LDSW];
  __shared__ _Float16 Bl[SPLIT ? 128 : 1][LDSW];

  const int tid = threadIdx.x;
  const int m0 = m_base + blockIdx.y * 128;
  const int n0 = blockIdx.x * 128;
  const int bb = m0 >> 9;            // batch (tiles never cross 512-row batches)

  const int lane = tid & 63;
  const int w    = tid >> 6;
  const int wr   = w >> 1, wc = w & 1;
  const int lr   = lane & 15;
  const int lkb  = (lane >> 4) * 8;

  const int srow = tid >> 1;         // staging: 2 threads per tile row
  const int scol = (tid & 1) * 16;

  const _Float16* A16 = (const _Float16*)Araw;
  const float*    A32 = (const float*)Araw;
  const float* Bsel = B0;
  if (MODE == MODE_UPMOD && mask[bb * H_DIM + n0 + srow]) Bsel = B1;
  const size_t arow = (size_t)(m0 + srow) * K + scol;
  const size_t brow = (size_t)(n0 + srow) * K + scol;

  f32x4 acc[4][4];
  #pragma unroll
  for (int i = 0; i < 4; i++)
    #pragma unroll
    for (int j = 0; j < 4; j++)
      acc[i][j] = (f32x4){0.f, 0.f, 0.f, 0.f};

  for (int kt = 0; kt < K; kt += 32){
    __syncthreads();
    if (AF16){
      *(f16x8*)&Ah[srow][scol]     = *(const f16x8*)(A16 + arow + kt);
      *(f16x8*)&Ah[srow][scol + 8] = *(const f16x8*)(A16 + arow + kt + 8);
      if (SPLIT){
        *(f16x8*)&Al[srow][scol]     = *(const f16x8*)(Alo2 + arow + kt);
        *(f16x8*)&Al[srow][scol + 8] = *(const f16x8*)(Alo2 + arow + kt + 8);
      }
    } else {
      #pragma unroll
      for (int j = 0; j < 4; j++){
        float4 f = *(const float4*)(A32 + arow + kt + 4*j);
        f16x4 h = { (_Float16)f.x, (_Float16)f.y, (_Float16)f.z, (_Float16)f.w };
        *(f16x4*)&Ah[srow][scol + 4*j] = h;
        if (SPLIT){
          f16x4 l = { (_Float16)(f.x-(float)h[0]), (_Float16)(f.y-(float)h[1]),
                      (_Float16)(f.z-(float)h[2]), (_Float16)(f.w-(float)h[3]) };
          *(f16x4*)&Al[srow][scol + 4*j] = l;
        }
      }
    }
    #pragma unroll
    for (int j = 0; j < 4; j++){
      float4 f = *(const float4*)(Bsel + brow + kt + 4*j);
      f16x4 h = { (_Float16)f.x, (_Float16)f.y, (_Float16)f.z, (_Float16)f.w };
      *(f16x4*)&Bh[srow][scol + 4*j] = h;
      if (SPLIT){
        f16x4 l = { (_Float16)(f.x-(float)h[0]), (_Float16)(f.y-(float)h[1]),
                    (_Float16)(f.z-(float)h[2]), (_Float16)(f.w-(float)h[3]) };
        *(f16x4*)&Bl[srow][scol + 4*j] = l;
      }
    }
    __syncthreads();

    f16x8 ah[4], bh[4], al[4], bl[4];
    #pragma unroll
    for (int i = 0; i < 4; i++){
      ah[i] = *(const f16x8*)&Ah[wr*64 + i*16 + lr][lkb];
      bh[i] = *(const f16x8*)&Bh[wc*64 + i*16 + lr][lkb];
      if (SPLIT){
        al[i] = *(const f16x8*)&Al[wr*64 + i*16 + lr][lkb];
        bl[i] = *(const f16x8*)&Bl[wc*64 + i*16 + lr][lkb];
      }
    }
    #pragma unroll
    for (int mi = 0; mi < 4; mi++)
      #pragma unroll
      for (int ni = 0; ni < 4; ni++){
        acc[mi][ni] = __builtin_amdgcn_mfma_f32_16x16x32_f16(ah[mi], bh[ni], acc[mi][ni], 0,0,0);
        if (SPLIT){
          acc[mi][ni] = __builtin_amdgcn_mfma_f32_16x16x32_f16(ah[mi], bl[ni], acc[mi][ni], 0,0,0);
          acc[mi][ni] = __builtin_amdgcn_mfma_f32_16x16x32_f16(al[mi], bh[ni], acc[mi][ni], 0,0,0);
        }
      }
  }

  // Epilogue.  C/D layout (m89): col = lane&15, row = (lane>>4)*4 + reg
  const int lq = lane >> 4;
  _Float16* C16 = (_Float16*)Craw;
  float*    C32 = (float*)Craw;

  #pragma unroll
  for (int ni = 0; ni < 4; ni++){
    const int gc = n0 + wc*64 + ni*16 + lr;
    float bias;
    if (MODE == MODE_UPMOD) bias = mask[bb*H_DIM + gc] ? bias1[gc] : bias0[gc];
    else                    bias = bias0[gc];
    unsigned colmax = 0u;
    #pragma unroll
    for (int mi = 0; mi < 4; mi++){
      #pragma unroll
      for (int r = 0; r < 4; r++){
        const int gr = m0 + wr*64 + mi*16 + lq*4 + r;
        float v = acc[mi][ni][r] + bias;
        if (MODE == MODE_G1){
          v = fmaxf(v, 0.f);
          _Float16 hh = (_Float16)v;
          C16[(size_t)gr*N + gc] = hh;
          Clo[(size_t)gr*N + gc] = (_Float16)(v - (float)hh);
        }
        if (MODE == MODE_UPMOD){
          v = v / (1.f + __expf(-v));
          C16[(size_t)gr*N + gc] = (_Float16)v;
        }
        if (MODE == MODE_DOWN) C32[(size_t)gr*N + gc] = v;
        if (MODE == MODE_G2){
          unsigned key = fenc(v);
          keys[(size_t)(gr - m_base)*N + gc] = key;
          colmax = max(colmax, key);
        }
      }
    }
    if (MODE == MODE_G2) atomicMax(&Mkey[bb*H_DIM + gc], colmax);
  }
}

// ---- exact k-th largest per batch: 4-pass radix select on 32-bit keys ----

__global__ void init_state(uint2* state){
  if (threadIdx.x < N_BATCH) state[threadIdx.x] = make_uint2(0u, K_SEL);
}

__global__ __launch_bounds__(256)
void hist_pass(const unsigned* __restrict__ keys, unsigned* __restrict__ hist,
               const uint2* __restrict__ state, int pass, int b0)
{
  __shared__ unsigned lh[256];
  const int bl = blockIdx.y;               // local batch 0..7
  const int b  = b0 + bl;
  lh[threadIdx.x] = 0;
  __syncthreads();
  const unsigned prefix = state[b].x;
  const int hishift  = 32 - 8*pass;
  const int binshift = 24 - 8*pass;
  const unsigned* p = keys + (size_t)bl * SH_PER_B + (size_t)blockIdx.x * (SH_PER_B/32);
  for (int i = threadIdx.x; i < SH_PER_B/32; i += 256){
    unsigned key = p[i];
    bool match = (pass == 0) || ((key >> hishift) == prefix);
    if (match) atomicAdd(&lh[(key >> binshift) & 255u], 1u);
  }
  __syncthreads();
  if (lh[threadIdx.x]) atomicAdd(&hist[(b << 8) + threadIdx.x], lh[threadIdx.x]);
}

__global__ void select_reduce(const unsigned* __restrict__ hist, uint2* __restrict__ state, int b0)
{
  const int b = b0 + blockIdx.x;
  if (threadIdx.x != 0) return;
  unsigned prefix = state[b].x;
  unsigned krem   = state[b].y;
  unsigned cum = 0;
  for (int bin = 255; bin >= 0; --bin){
    unsigned c = hist[(b << 8) + bin];
    if (cum + c >= krem){
      state[b].x = (prefix << 8) | (unsigned)bin;
      state[b].y = krem - cum;
      return;
    }
    cum += c;
  }
}

__global__ __launch_bounds__(256)
void make_mask(const unsigned* __restrict__ Mkey, const uint2* __restrict__ state,
               unsigned* __restrict__ mask){
  const int i = blockIdx.x * 256 + threadIdx.x;   // B*H = 65536
  const int b = i >> 12;
  mask[i] = (Mkey[i] >= state[b].x) ? 1u : 0u;    // exact 32-bit key compare
}

extern "C" void kernel_launch(void* const* d_in, const int* in_sizes, int n_in,
                              void* d_out, int out_size, void* d_ws, size_t ws_size,
                              hipStream_t stream)
{
  (void)in_sizes; (void)n_in; (void)out_size; (void)ws_size;
  const float* X      = (const float*)d_in[0];
  const float* up_w   = (const float*)d_in[1];
  const float* up_b   = (const float*)d_in[2];
  const float* g1w    = (const float*)d_in[3];
  const float* g1b    = (const float*)d_in[4];
  const float* g2w    = (const float*)d_in[5];
  const float* g2b    = (const float*)d_in[6];
  const float* mod_w  = (const float*)d_in[7];
  const float* mod_b  = (const float*)d_in[8];
  const float* down_w = (const float*)d_in[9];
  const float* down_b = (const float*)d_in[10];
  float* out = (float*)d_out;

  // ws layout (peak 192.6 MiB; round-0 crash = 269 MiB overflow of ~256 MiB ws)
  char* ws = (char*)d_ws;
  _Float16* Fhi  = (_Float16*)ws;                            // 64 MiB [8192][4096]
  _Float16* Flo  = (_Float16*)(ws + (64ull<<20));            // 64 MiB
  unsigned* keys = (unsigned*)(ws + (128ull<<20));           // 64 MiB (half-batch keys)
  unsigned* Mkey = (unsigned*)(ws + (192ull<<20));           // 256 KB
  unsigned* maskb= (unsigned*)(ws + (192ull<<20) + 262144);  // 256 KB
  unsigned* hist = (unsigned*)(ws + (192ull<<20) + 524288);  // 64 KB (4 passes x 16 x 256)
  uint2*    state= (uint2*)   (ws + (192ull<<20) + 589824);  // 128 B
  _Float16* Hbuf = Fhi;                                      // reuse after gate2

  hipMemsetAsync(Mkey, 0, 262144, stream);
  hipMemsetAsync(hist, 0, 65536, stream);
  init_state<<<1, 64, 0, stream>>>(state);

  // gate1 (split): Fhi/Flo = split(relu(X @ g1w^T + g1b))   [8192 x 4096], K=1024
  gemm_bt<MODE_G1, true, false><<<dim3(32, 64), 256, 0, stream>>>(
      X, nullptr, g1w, nullptr, g1b, nullptr, nullptr,
      Fhi, Flo, nullptr, nullptr, BS_ROWS, H_DIM, D_DIM, 0);

  // gate2 (split), two half-batches; exact radix select per half
  for (int half = 0; half < 2; half++){
    gemm_bt<MODE_G2, true, true><<<dim3(32, 32), 256, 0, stream>>>(
        Fhi, Flo, g2w, nullptr, g2b, nullptr, nullptr,
        nullptr, nullptr, keys, Mkey, BS_ROWS, H_DIM, H_DIM, half * 4096);
    const int b0 = half * 8;
    for (int p = 0; p < 4; p++){
      hist_pass<<<dim3(32, 8), 256, 0, stream>>>(keys, hist + p*4096, state, p, b0);
      select_reduce<<<8, 64, 0, stream>>>(hist + p*4096, state, b0);
    }
  }
  make_mask<<<256, 256, 0, stream>>>(Mkey, state, maskb);

  // up/mod row-select + silu -> Hbuf   [8192 x 4096], K=1024, plain fp16
  gemm_bt<MODE_UPMOD, false, false><<<dim3(32, 64), 256, 0, stream>>>(
      X, nullptr, up_w, mod_w, up_b, mod_b, maskb,
      Hbuf, nullptr, nullptr, nullptr, BS_ROWS, H_DIM, D_DIM, 0);

  // down: out = Hbuf @ down_w^T + down_b   [8192 x 1024], K=4096, plain fp16
  gemm_bt<MODE_DOWN, false, true><<<dim3(8, 64), 256, 0, stream>>>(
      Hbuf, nullptr, down_w, nullptr, down_b, nullptr, nullptr,
      out, nullptr, nullptr, nullptr, BS_ROWS, D_DIM, H_DIM, 0);
}

// Round 5
// 2122.908 us; speedup vs baseline: 1.0198x; 1.0198x over previous
//
#include <hip/hip_runtime.h>
#include <cstdint>

typedef __attribute__((ext_vector_type(4))) _Float16 f16x4;
typedef __attribute__((ext_vector_type(8))) _Float16 f16x8;
typedef __attribute__((ext_vector_type(4))) float f32x4;

#define D_DIM 1024
#define H_DIM 4096
#define BS_ROWS 8192
#define K_SEL 524288u

__device__ __forceinline__ unsigned fenc(float v){
  unsigned u = __float_as_uint(v);
  return (u & 0x80000000u) ? ~u : (u | 0x80000000u);
}

// async global->LDS, 16B per lane (dest = wave-uniform base + lane*16)
__device__ __forceinline__ void gload16(const _Float16* g, _Float16* l){
  __builtin_amdgcn_global_load_lds(
      (const __attribute__((address_space(1))) void*)g,
      (__attribute__((address_space(3))) void*)l, 16, 0, 0);
}

// Tiled fp16 image: tiles of 128 rows x 32 halves (8KB, 512 granules of 16B).
// Granule for logical (row, k8): p = (row&127)>>1,
// slot s = ((row&1)<<2 | (k8&3)) ^ (p&7); granule index = p*8 + s.
// Per 16-lane quarter-wave fragment read each slot s is hit exactly 2x -> conflict-free.
__device__ __forceinline__ size_t img_g32(int row, int k8, int nkt32){
  int p = (row & 127) >> 1;
  int s = (((row & 1) << 2) | (k8 & 3)) ^ (p & 7);
  return ((size_t)((row >> 7) * nkt32 + (k8 >> 2)) << 9) + (p << 3) + s;
}

template<bool LO>
__global__ __launch_bounds__(256)
void pack_img(const float* __restrict__ W, _Float16* __restrict__ hi,
              _Float16* __restrict__ lo, int k8shift, int nkt32, int total)
{
  int g = blockIdx.x * 256 + threadIdx.x;
  if (g >= total) return;
  int row = g >> k8shift, k8 = g & ((1 << k8shift) - 1);
  const float* src = W + ((size_t)row << (k8shift + 3)) + (k8 << 3);
  float4 f0 = *(const float4*)src, f1 = *(const float4*)(src + 4);
  float ff[8] = {f0.x,f0.y,f0.z,f0.w,f1.x,f1.y,f1.z,f1.w};
  f16x8 hv, lv;
  #pragma unroll
  for (int i = 0; i < 8; i++){
    hv[i] = (_Float16)ff[i];
    if (LO) lv[i] = (_Float16)(ff[i] - (float)hv[i]);
  }
  size_t d = img_g32(row, k8, nkt32) << 3;
  *(f16x8*)&hi[d] = hv;
  if (LO) *(f16x8*)&lo[d] = lv;
}

enum { MODE_G1 = 0, MODE_G2 = 1, MODE_UPMOD = 2, MODE_DOWN = 3 };

// C = A[M,K] * B[N,K]^T + bias.  A/B are tiled fp16 images.
// NSEG==3 (G1,G2): acc = Ahi*Bhi + Alo*Bhi + Ahi*Blo  (~fp32 accuracy)
template<int MODE>
__global__ __launch_bounds__(256)
void gemm_t(const _Float16* __restrict__ Ahi, const _Float16* __restrict__ Alo,
            const _Float16* __restrict__ Bhi, const _Float16* __restrict__ Blo,
            const float* __restrict__ bias0, const float* __restrict__ bias1,
            const unsigned* __restrict__ mask,
            _Float16* __restrict__ Chi, _Float16* __restrict__ Clo,
            float* __restrict__ C32,
            unsigned* __restrict__ keys, unsigned* __restrict__ Mkey,
            int N, int K, int m_img_base, int c_row_base, int batch_base)
{
  constexpr int NSEG = (MODE == MODE_G1 || MODE == MODE_G2) ? 3 : 1;
  constexpr bool BSEL = (MODE == MODE_UPMOD);
  __shared__ __align__(16) _Float16 sAhi[4096];
  __shared__ __align__(16) _Float16 sBhi[4096];
  __shared__ __align__(16) _Float16 sAlo[NSEG == 3 ? 4096 : 16];
  __shared__ __align__(16) _Float16 sBlo[NSEG == 3 ? 4096 : 16];

  // XCD-aware block swizzle (all grids have nwg % 8 == 0)
  const int nbx = gridDim.x;
  int wg = blockIdx.y * nbx + blockIdx.x;
  const int nwg = nbx * gridDim.y;
  wg = (wg & 7) * (nwg >> 3) + (wg >> 3);
  const int bx = wg % nbx, by = wg / nbx;

  const int tid = threadIdx.x;
  const int lane = tid & 63;
  const int w  = tid >> 6;
  const int wr = w >> 1, wc = w & 1;
  const int lr = lane & 15;
  const int q  = lane >> 4;

  const int m0 = m_img_base + by * 128;
  const int n0 = bx * 128;
  const int nkt = K >> 5;
  const size_t arow = (size_t)(m0 >> 7) * nkt;
  const size_t brow = (size_t)(n0 >> 7) * nkt;

  // UPMOD: per-staged-granule row mask (2 granules per thread per tile)
  int bsel_m[2];
  if (BSEL){
    const int bb = m0 >> 9;
    #pragma unroll
    for (int i = 0; i < 2; i++){
      int g = tid + (i << 8);
      int p = g >> 3, s = (g & 7) ^ (p & 7);
      int row = (p << 1) | (s >> 2);
      bsel_m[i] = mask[bb * H_DIM + n0 + row] ? 1 : 0;
    }
  }

  f32x4 acc[4][4];
  #pragma unroll
  for (int i = 0; i < 4; i++)
    #pragma unroll
    for (int j = 0; j < 4; j++) acc[i][j] = (f32x4){0.f,0.f,0.f,0.f};

  const int soff = (((((lr & 1) << 2) | q) ^ (lr >> 1)) << 3);  // s*8, lane-const

  for (int kt = 0; kt < nkt; ++kt){
    __syncthreads();
    {
      const _Float16* at = Ahi + ((arow + kt) << 12);
      #pragma unroll
      for (int j = 0; j < 2; j++)
        gload16(at + ((w*2 + j) << 9) + (lane << 3), sAhi + ((w*2 + j) << 9));
      if (NSEG == 3){
        const _Float16* alt = Alo + ((arow + kt) << 12);
        const _Float16* bht = Bhi + ((brow + kt) << 12);
        const _Float16* blt = Blo + ((brow + kt) << 12);
        #pragma unroll
        for (int j = 0; j < 2; j++){
          gload16(alt + ((w*2 + j) << 9) + (lane << 3), sAlo + ((w*2 + j) << 9));
          gload16(bht + ((w*2 + j) << 9) + (lane << 3), sBhi + ((w*2 + j) << 9));
          gload16(blt + ((w*2 + j) << 9) + (lane << 3), sBlo + ((w*2 + j) << 9));
        }
      } else if (!BSEL){
        const _Float16* bt = Bhi + ((brow + kt) << 12);
        #pragma unroll
        for (int j = 0; j < 2; j++)
          gload16(bt + ((w*2 + j) << 9) + (lane << 3), sBhi + ((w*2 + j) << 9));
      } else {
        const size_t toff = (brow + kt) << 12;
        #pragma unroll
        for (int i = 0; i < 2; i++){
          int g = tid + (i << 8);
          const _Float16* src = (bsel_m[i] ? Blo : Bhi) + toff + ((size_t)g << 3);
          *(f16x8*)&sBhi[g << 3] = *(const f16x8*)src;
        }
      }
    }
    __syncthreads();

    f16x8 fah[4], fbh[4], fal[4], fbl[4];
    #pragma unroll
    for (int i = 0; i < 4; i++){
      const int ap = (wr*32 + i*8 + (lr >> 1)) << 6;   // p*64 halves (r4 bug: was <<7, OOB)
      const int bp = (wc*32 + i*8 + (lr >> 1)) << 6;
      fah[i] = *(const f16x8*)&sAhi[ap + soff];
      fbh[i] = *(const f16x8*)&sBhi[bp + soff];
      if (NSEG == 3){
        fal[i] = *(const f16x8*)&sAlo[ap + soff];
        fbl[i] = *(const f16x8*)&sBlo[bp + soff];
      }
    }
    #pragma unroll
    for (int mi = 0; mi < 4; mi++)
      #pragma unroll
      for (int ni = 0; ni < 4; ni++)
        acc[mi][ni] = __builtin_amdgcn_mfma_f32_16x16x32_f16(fah[mi], fbh[ni], acc[mi][ni], 0,0,0);
    if (NSEG == 3){
      #pragma unroll
      for (int mi = 0; mi < 4; mi++)
        #pragma unroll
        for (int ni = 0; ni < 4; ni++)
          acc[mi][ni] = __builtin_amdgcn_mfma_f32_16x16x32_f16(fal[mi], fbh[ni], acc[mi][ni], 0,0,0);
      #pragma unroll
      for (int mi = 0; mi < 4; mi++)
        #pragma unroll
        for (int ni = 0; ni < 4; ni++)
          acc[mi][ni] = __builtin_amdgcn_mfma_f32_16x16x32_f16(fah[mi], fbl[ni], acc[mi][ni], 0,0,0);
    }
  }

  // Epilogue.  C/D layout (m89): col = lane&15, row = (lane>>4)*4 + reg
  #pragma unroll
  for (int ni = 0; ni < 4; ni++){
    const int gc = n0 + wc*64 + ni*16 + lr;
    float bias;
    if (MODE == MODE_UPMOD) bias = mask[(m0 >> 9) * H_DIM + gc] ? bias1[gc] : bias0[gc];
    else                    bias = bias0[gc];
    unsigned colmax = 0u;
    #pragma unroll
    for (int mi = 0; mi < 4; mi++){
      #pragma unroll
      for (int r = 0; r < 4; r++){
        const int gr = m0 + wr*64 + mi*16 + q*4 + r;
        const int cr = gr - c_row_base;
        float v = acc[mi][ni][r] + bias;
        if (MODE == MODE_G1){
          v = fmaxf(v, 0.f);
          _Float16 hh = (_Float16)v;
          size_t d = (img_g32(cr, gc >> 3, N >> 5) << 3) + (gc & 7);
          Chi[d] = hh;
          Clo[d] = (_Float16)(v - (float)hh);
        }
        if (MODE == MODE_UPMOD){
          v = v / (1.f + __expf(-v));
          size_t d = (img_g32(cr, gc >> 3, N >> 5) << 3) + (gc & 7);
          Chi[d] = (_Float16)v;
        }
        if (MODE == MODE_DOWN) C32[(size_t)cr * N + gc] = v;
        if (MODE == MODE_G2){
          unsigned key = fenc(v);
          keys[(size_t)cr * N + gc] = key;
          colmax = max(colmax, key);
        }
      }
    }
    if (MODE == MODE_G2)
      atomicMax(&Mkey[(batch_base + (m0 >> 9)) * H_DIM + gc], colmax);
  }
}

// ---- exact k-th largest per batch: 4-pass radix select on 32-bit keys ----

__global__ void init_state(uint2* state){
  if (threadIdx.x < 16) state[threadIdx.x] = make_uint2(0u, K_SEL);
}

__global__ __launch_bounds__(256)
void hist_pass(const unsigned* __restrict__ keys, unsigned* __restrict__ hist,
               const uint2* __restrict__ state, int pass, int b0)
{
  __shared__ unsigned lh[256];
  const int bl = blockIdx.y;           // local batch 0..3 in quarter
  const int b  = b0 + bl;
  lh[threadIdx.x] = 0;
  __syncthreads();
  const unsigned prefix = state[b].x;
  const int hishift  = 32 - 8*pass;
  const int binshift = 24 - 8*pass;
  const unsigned* p = keys + (size_t)bl * 2097152u + (size_t)blockIdx.x * 65536u;
  for (int i = threadIdx.x; i < 65536; i += 256){
    unsigned key = p[i];
    bool match = (pass == 0) || ((key >> hishift) == prefix);
    if (match) atomicAdd(&lh[(key >> binshift) & 255u], 1u);
  }
  __syncthreads();
  if (lh[threadIdx.x]) atomicAdd(&hist[(b << 8) + threadIdx.x], lh[threadIdx.x]);
}

__global__ void select_reduce(const unsigned* __restrict__ hist, uint2* __restrict__ state, int b0)
{
  const int b = b0 + blockIdx.x;
  if (threadIdx.x != 0) return;
  unsigned prefix = state[b].x;
  unsigned krem   = state[b].y;
  unsigned cum = 0;
  for (int bin = 255; bin >= 0; --bin){
    unsigned c = hist[(b << 8) + bin];
    if (cum + c >= krem){
      state[b].x = (prefix << 8) | (unsigned)bin;
      state[b].y = krem - cum;
      return;
    }
    cum += c;
  }
}

__global__ __launch_bounds__(256)
void make_mask(const unsigned* __restrict__ Mkey, const uint2* __restrict__ state,
               unsigned* __restrict__ mask){
  const int i = blockIdx.x * 256 + threadIdx.x;   // B*H = 65536
  const int b = i >> 12;
  mask[i] = (Mkey[i] >= state[b].x) ? 1u : 0u;
}

extern "C" void kernel_launch(void* const* d_in, const int* in_sizes, int n_in,
                              void* d_out, int out_size, void* d_ws, size_t ws_size,
                              hipStream_t stream)
{
  (void)in_sizes; (void)n_in; (void)out_size; (void)ws_size;
  const float* X      = (const float*)d_in[0];
  const float* up_w   = (const float*)d_in[1];
  const float* up_b   = (const float*)d_in[2];
  const float* g1w    = (const float*)d_in[3];
  const float* g1b    = (const float*)d_in[4];
  const float* g2w    = (const float*)d_in[5];
  const float* g2b    = (const float*)d_in[6];
  const float* mod_w  = (const float*)d_in[7];
  const float* mod_b  = (const float*)d_in[8];
  const float* down_w = (const float*)d_in[9];
  const float* down_b = (const float*)d_in[10];
  float* out = (float*)d_out;

  // ws layout, MiB offsets (peak ~233 MiB)
  char* ws = (char*)d_ws;
  _Float16* Xhi  = (_Float16*)(ws);
  _Float16* Xlo  = (_Float16*)(ws + (16ull<<20));
  _Float16* G1hi = (_Float16*)(ws + (32ull<<20));
  _Float16* G1lo = (_Float16*)(ws + (40ull<<20));
  _Float16* G2hi = (_Float16*)(ws + (48ull<<20));
  _Float16* G2lo = (_Float16*)(ws + (80ull<<20));
  _Float16* UPhi = (_Float16*)(ws + (112ull<<20));
  _Float16* MODhi= (_Float16*)(ws + (120ull<<20));
  _Float16* DWhi = (_Float16*)(ws + (128ull<<20));
  _Float16* Fhi  = (_Float16*)(ws + (136ull<<20));   // per-half [4096][4096]
  _Float16* Flo  = (_Float16*)(ws + (168ull<<20));
  _Float16* Hbuf = (_Float16*)(ws + (136ull<<20));   // reuse after selection
  unsigned* keys = (unsigned*)(ws + (200ull<<20));   // per-quarter [2048][4096]
  unsigned* Mkey = (unsigned*)(ws + (232ull<<20));
  unsigned* maskb= (unsigned*)(ws + (232ull<<20) + 262144);
  unsigned* hist = (unsigned*)(ws + (232ull<<20) + 524288);
  uint2*    state= (uint2*)   (ws + (232ull<<20) + 589824);

  // pack fp32 -> tiled fp16 images (hi/lo where precision requires)
  pack_img<true ><<<4096, 256, 0, stream>>>(X,      Xhi,  Xlo,  7, 32,  1048576);
  pack_img<true ><<<2048, 256, 0, stream>>>(g1w,    G1hi, G1lo, 7, 32,  524288);
  pack_img<true ><<<8192, 256, 0, stream>>>(g2w,    G2hi, G2lo, 9, 128, 2097152);
  pack_img<false><<<2048, 256, 0, stream>>>(up_w,   UPhi, nullptr, 7, 32,  524288);
  pack_img<false><<<2048, 256, 0, stream>>>(mod_w,  MODhi,nullptr, 7, 32,  524288);
  pack_img<false><<<2048, 256, 0, stream>>>(down_w, DWhi, nullptr, 9, 128, 524288);

  hipMemsetAsync(Mkey, 0, 262144, stream);
  hipMemsetAsync(hist, 0, 65536, stream);
  init_state<<<1, 64, 0, stream>>>(state);

  for (int half = 0; half < 2; ++half){
    // gate1 half: F = split(relu(X @ g1w^T + g1b))  [4096 x 4096], K=1024
    gemm_t<MODE_G1><<<dim3(32,32), 256, 0, stream>>>(
        Xhi, Xlo, G1hi, G1lo, g1b, nullptr, nullptr,
        Fhi, Flo, nullptr, nullptr, nullptr, H_DIM, D_DIM, half*4096, half*4096, 0);
    for (int qd = 0; qd < 2; ++qd){
      // gate2 quarter: keys + Mkey  [2048 x 4096], K=4096
      gemm_t<MODE_G2><<<dim3(32,16), 256, 0, stream>>>(
          Fhi, Flo, G2hi, G2lo, g2b, nullptr, nullptr,
          nullptr, nullptr, nullptr, keys, Mkey, H_DIM, H_DIM, qd*2048, qd*2048, half*8);
      const int b0 = half*8 + qd*4;
      for (int p = 0; p < 4; p++){
        hist_pass<<<dim3(32,4), 256, 0, stream>>>(keys, hist + p*4096, state, p, b0);
        select_reduce<<<4, 64, 0, stream>>>(hist + p*4096, state, b0);
      }
    }
  }
  make_mask<<<256, 256, 0, stream>>>(Mkey, state, maskb);

  // up/mod row-select + silu -> Hbuf image  [8192 x 4096], K=1024
  gemm_t<MODE_UPMOD><<<dim3(32,64), 256, 0, stream>>>(
      Xhi, nullptr, UPhi, MODhi, up_b, mod_b, maskb,
      Hbuf, nullptr, nullptr, nullptr, nullptr, H_DIM, D_DIM, 0, 0, 0);
  // down: out = Hbuf @ down_w^T + down_b  [8192 x 1024], K=4096
  gemm_t<MODE_DOWN><<<dim3(8,64), 256, 0, stream>>>(
      Hbuf, nullptr, DWhi, nullptr, down_b, nullptr, nullptr,
      nullptr, nullptr, out, nullptr, nullptr, D_DIM, H_DIM, 0, 0, 0);
}